// Round 18
// baseline (160.602 us; speedup 1.0000x reference)
//
#include <hip/hip_runtime.h>
#include <hip/hip_bf16.h>
#include <stdint.h>
#include <math.h>

#define B_   2
#define L_   3072
#define K_   48
#define FDIM 416
#define NOUT 128
#define FRS8 424    // F row stride (fp8 bytes), 8B-aligned
#define NLUT 1920   // RBF LUT entries: D in [0,30) step 1/64

// PAIRC[dd] = ai*8+bi for pair dd (dd = 1..24 uses PAIRC[dd-1])
__device__ const unsigned char PAIRC[24] = {
    0, 18, 27, 36, 8, 10, 11, 12, 2, 3, 4, 34, 35, 26,
    1, 17, 25, 33, 16, 24, 32, 20, 28, 19
};

typedef __attribute__((ext_vector_type(4))) float f32x4;

// ---------- kernel P: Wt8 fragment-order fp8 (paired-column) + RBF LUT + frames ----------
__global__ __launch_bounds__(256) void k_prep(const float* __restrict__ X,
                                              const float* __restrict__ mask,
                                              const float* __restrict__ edgeW,
                                              float* __restrict__ atoms,
                                              float* __restrict__ CaA4,
                                              unsigned char* __restrict__ Wt8,
                                              uint4* __restrict__ LUT)
{
    const int bid = blockIdx.x;
    if (bid < 52) {
        int idx4 = bid * 256 + threadIdx.x;        // dword index, 0..13311
        int b = idx4 * 4;
        int lhi = (b >> 3) & 3;
        int l15 = (b >> 5) & 15;
        int nt  = (b >> 9) & 7;
        int kt  = b >> 12;
        int n = (nt >> 1) * 32 + 2 * l15 + (nt & 1);
        int kbase = kt * 32 + lhi * 8 + (b & 7);
        float v0 = edgeW[(kbase + 0) * NOUT + n];
        float v1 = edgeW[(kbase + 1) * NOUT + n];
        float v2 = edgeW[(kbase + 2) * NOUT + n];
        float v3 = edgeW[(kbase + 3) * NOUT + n];
        int w = __builtin_amdgcn_cvt_pk_fp8_f32(v0, v1, 0, false);
        w = __builtin_amdgcn_cvt_pk_fp8_f32(v2, v3, w, true);
        ((unsigned int*)Wt8)[idx4] = (unsigned int)w;
    } else if (bid < 60) {
        int e = (bid - 52) * 256 + threadIdx.x;    // LUT entry
        if (e >= NLUT) return;
        float D = (float)e * 0.015625f;            // 1/64
        float z = (D - 2.0f) * 0.8f;
        unsigned int u[4];
        #pragma unroll
        for (int p = 0; p < 4; ++p) {
            float e0 = __expf(-(z * z)); z -= 1.0666667f;
            float e1 = __expf(-(z * z)); z -= 1.0666667f;
            float e2 = __expf(-(z * z)); z -= 1.0666667f;
            float e3 = __expf(-(z * z)); z -= 1.0666667f;
            int w = __builtin_amdgcn_cvt_pk_fp8_f32(e0, e1, 0, false);
            w = __builtin_amdgcn_cvt_pk_fp8_f32(e2, e3, w, true);
            u[p] = (unsigned int)w;
        }
        LUT[e] = make_uint4(u[0], u[1], u[2], u[3]);
    } else {
        int row = (bid - 60) * 256 + threadIdx.x;
        if (row >= B_ * L_) return;
        const float* x = X + row * 12;
        float nx = x[0], ny = x[1], nz = x[2];
        float cax = x[3], cay = x[4], caz = x[5];
        float cx = x[6], cy = x[7], cz = x[8];
        float ox = x[9], oy = x[10], oz = x[11];
        float bx = cax - nx, by = cay - ny, bz = caz - nz;
        float vx = cx - cax, vy = cy - cay, vz = cz - caz;
        float axv = by * vz - bz * vy;
        float ayv = bz * vx - bx * vz;
        float azv = bx * vy - by * vx;
        float cbx = -0.58273431f * axv + 0.56802827f * bx - 0.54067466f * vx + cax;
        float cby = -0.58273431f * ayv + 0.56802827f * by - 0.54067466f * vy + cay;
        float cbz = -0.58273431f * azv + 0.56802827f * bz - 0.54067466f * vz + caz;
        float* A = atoms + row * 16;
        A[0] = nx;  A[1] = ny;  A[2] = nz;
        A[3] = cax; A[4] = cay; A[5] = caz;
        A[6] = cx;  A[7] = cy;  A[8] = cz;
        A[9] = ox;  A[10] = oy; A[11] = oz;
        A[12] = cbx; A[13] = cby; A[14] = cbz;
        A[15] = 0.f;
        float4 c4 = make_float4(cax, cay, caz, mask[row]);
        *(float4*)(CaA4 + row * 4) = c4;
    }
}

// ---- kernel B: top-48 for TWO rows per block. One CaA4 stream serves both.
// ---- Per-row: f32 dist^2 bucketing (2048 buckets, +2 slop) -> f64 refine -> bitonic.
__global__ __launch_bounds__(256) void k_topk(const float* __restrict__ CaA4,
                                              int* __restrict__ eidx,
                                              float* __restrict__ dnb,
                                              float* __restrict__ out_eidx_f)
{
    __shared__ __align__(16) unsigned int SH[5632];   // 22.5 KB
    // layout: hist0 = SH[0..2047], hist1 = SH[2048..4095], candJ = SH[4096..5631] (2x768)
    // candK overlays SH[0..4095] as u64[2048]: row0 -> [0..1023], row1 -> [1024..2047]
    __shared__ unsigned int swave[4];
    __shared__ int sP[2];
    __shared__ unsigned int sCnt[2];

    const int row0 = blockIdx.x * 2;
    const int row1 = row0 + 1;
    const int b = row0 / L_;
    const int tid = threadIdx.x;
    const int lane = tid & 63;
    const int wv = tid >> 6;

    #pragma unroll
    for (int i = 0; i < 16; ++i) SH[tid + 256 * i] = 0;
    if (tid < 2) sCnt[tid] = 0;

    const float4 me0 = *(const float4*)(CaA4 + row0 * 4);
    const float4 me1 = *(const float4*)(CaA4 + row1 * 4);
    const float4* Cb = (const float4*)(CaA4 + (size_t)b * L_ * 4);
    __syncthreads();

    unsigned int bits0[12], bits1[12];
    #pragma unroll
    for (int m = 0; m < 12; ++m) {
        int j = tid + 256 * m;
        float4 nb = Cb[j];
        float dx0 = me0.x - nb.x, dy0 = me0.y - nb.y, dz0 = me0.z - nb.z;
        float s0 = fmaf(dz0, dz0, fmaf(dy0, dy0, dx0 * dx0)) + 1e-6f;
        bits0[m] = ((me0.w * nb.w) != 0.0f) ? __float_as_uint(s0) : 0x7F800000u;
        float dx1 = me1.x - nb.x, dy1 = me1.y - nb.y, dz1 = me1.z - nb.z;
        float s1 = fmaf(dz1, dz1, fmaf(dy1, dy1, dx1 * dx1)) + 1e-6f;
        bits1[m] = ((me1.w * nb.w) != 0.0f) ? __float_as_uint(s1) : 0x7F800000u;
        atomicAdd(&SH[bits0[m] >> 20], 1u);
        atomicAdd(&SH[2048 + (bits1[m] >> 20)], 1u);
    }
    __syncthreads();

    // two sequential block scans (2048 buckets each)
    #pragma unroll
    for (int r2 = 0; r2 < 2; ++r2) {
        unsigned int loc[8];
        unsigned int s = 0;
        #pragma unroll
        for (int i = 0; i < 8; ++i) { loc[i] = SH[r2 * 2048 + tid * 8 + i]; s += loc[i]; }
        unsigned int sc = s;
        #pragma unroll
        for (int off = 1; off < 64; off <<= 1) {
            unsigned int o = __shfl_up(sc, off);
            if (lane >= off) sc += o;
        }
        if (lane == 63) swave[wv] = sc;
        __syncthreads();
        unsigned int base = 0;
        #pragma unroll
        for (int w = 0; w < 4; ++w) if (w < wv) base += swave[w];
        unsigned int cum = base + sc - s;
        #pragma unroll
        for (int i = 0; i < 8; ++i) {
            unsigned int c = loc[i];
            if (cum < K_ && cum + c >= K_) sP[r2] = tid * 8 + i;
            cum += c;
        }
        __syncthreads();
    }
    const unsigned int Pth0 = (unsigned int)sP[0] + 2;
    const unsigned int Pth1 = (unsigned int)sP[1] + 2;

    unsigned int* candJ = SH + 4096;
    #pragma unroll
    for (int m = 0; m < 12; ++m) {
        if ((bits0[m] >> 20) <= Pth0) {
            unsigned int pos = atomicAdd(&sCnt[0], 1u);
            if (pos < 768) candJ[pos] = (unsigned)(tid + 256 * m);
        }
        if ((bits1[m] >> 20) <= Pth1) {
            unsigned int pos = atomicAdd(&sCnt[1], 1u);
            if (pos < 768) candJ[768 + pos] = (unsigned)(tid + 256 * m);
        }
    }
    __syncthreads();
    int cnt0 = (int)sCnt[0]; if (cnt0 > 768) cnt0 = 768;
    int cnt1 = (int)sCnt[1]; if (cnt1 > 768) cnt1 = 768;

    unsigned long long* candK = (unsigned long long*)SH;   // hist region dead
    {
        const double cax = (double)me0.x, cay = (double)me0.y, caz = (double)me0.z;
        for (int i = tid; i < cnt0; i += 256) {
            int j = (int)candJ[i];
            float4 nb = Cb[j];
            double dx = cax - (double)nb.x;
            double dy = cay - (double)nb.y;
            double dz = caz - (double)nb.z;
            double ss = dx * dx;
            ss = ss + dy * dy;
            ss = ss + dz * dz;
            ss = ss + 1e-6;
            float v = (float)sqrt(ss);
            candK[i] = ((unsigned long long)__float_as_uint(v) << 32) | (unsigned)j;
        }
    }
    {
        const double cax = (double)me1.x, cay = (double)me1.y, caz = (double)me1.z;
        for (int i = tid; i < cnt1; i += 256) {
            int j = (int)candJ[768 + i];
            float4 nb = Cb[j];
            double dx = cax - (double)nb.x;
            double dy = cay - (double)nb.y;
            double dz = caz - (double)nb.z;
            double ss = dx * dx;
            ss = ss + dy * dy;
            ss = ss + dz * dz;
            ss = ss + 1e-6;
            float v = (float)sqrt(ss);
            candK[1024 + i] = ((unsigned long long)__float_as_uint(v) << 32) | (unsigned)j;
        }
    }
    __syncthreads();

    const bool small0 = (cnt0 <= 64), small1 = (cnt1 <= 64);
    // parallel wave sorts for the common case
    if (small0 && wv == 0) {
        unsigned long long k = (lane < cnt0) ? candK[lane] : ~0ull;
        #pragma unroll
        for (int size = 2; size <= 64; size <<= 1) {
            #pragma unroll
            for (int stride = size >> 1; stride >= 1; stride >>= 1) {
                unsigned long long o = __shfl_xor(k, stride);
                bool low = (lane & stride) == 0;
                bool up = (lane & size) == 0 || size == 64;
                unsigned long long mn = k < o ? k : o;
                unsigned long long mx = k < o ? o : k;
                k = (low == up) ? mn : mx;
            }
        }
        if (lane < K_) {
            int gj = (int)(unsigned)(k & 0xffffffffu);
            eidx[row0 * K_ + lane] = gj;
            dnb[row0 * K_ + lane] = __uint_as_float((unsigned)(k >> 32));
            out_eidx_f[row0 * K_ + lane] = (float)gj;
        }
    }
    if (small1 && wv == 1) {
        unsigned long long k = (lane < cnt1) ? candK[1024 + lane] : ~0ull;
        #pragma unroll
        for (int size = 2; size <= 64; size <<= 1) {
            #pragma unroll
            for (int stride = size >> 1; stride >= 1; stride >>= 1) {
                unsigned long long o = __shfl_xor(k, stride);
                bool low = (lane & stride) == 0;
                bool up = (lane & size) == 0 || size == 64;
                unsigned long long mn = k < o ? k : o;
                unsigned long long mx = k < o ? o : k;
                k = (low == up) ? mn : mx;
            }
        }
        if (lane < K_) {
            int gj = (int)(unsigned)(k & 0xffffffffu);
            eidx[row1 * K_ + lane] = gj;
            dnb[row1 * K_ + lane] = __uint_as_float((unsigned)(k >> 32));
            out_eidx_f[row1 * K_ + lane] = (float)gj;
        }
    }
    // uniform-branch block-sort fallbacks (rare)
    #pragma unroll
    for (int r2 = 0; r2 < 2; ++r2) {
        int cnt = r2 ? cnt1 : cnt0;
        bool small = r2 ? small1 : small0;
        if (small) continue;
        unsigned long long* ck = candK + r2 * 1024;
        int rowg = r2 ? row1 : row0;
        int M2 = 128;
        while (M2 < cnt) M2 <<= 1;
        for (int i = cnt + tid; i < M2; i += 256) ck[i] = ~0ull;
        for (int size = 2; size <= M2; size <<= 1) {
            for (int stride = size >> 1; stride > 0; stride >>= 1) {
                __syncthreads();
                for (int i = tid; i < M2; i += 256) {
                    int p = i ^ stride;
                    if (p > i) {
                        unsigned long long a = ck[i];
                        unsigned long long c2 = ck[p];
                        bool up = ((i & size) == 0);
                        if ((a > c2) == up) { ck[i] = c2; ck[p] = a; }
                    }
                }
            }
        }
        __syncthreads();
        if (tid < K_) {
            unsigned long long g = ck[tid];
            int gj = (int)(unsigned)(g & 0xffffffffu);
            eidx[rowg * K_ + tid] = gj;
            dnb[rowg * K_ + tid] = __uint_as_float((unsigned)(g >> 32));
            out_eidx_f[rowg * K_ + tid] = (float)gj;
        }
    }
}

// ---------------- kernel C: TWO rows/block: features -> fp8 MFMA 96x416x128 -> LN ----------------
__global__ __launch_bounds__(256) void k_edge(const float* __restrict__ atoms,
                                              const int* __restrict__ eidx,
                                              const float* __restrict__ dnb,
                                              const int* __restrict__ Ridx,
                                              const int* __restrict__ chain,
                                              const float* __restrict__ posW,
                                              const float* __restrict__ posb,
                                              const unsigned char* __restrict__ Wt8,
                                              const uint4* __restrict__ LUT,
                                              const float* __restrict__ gamma,
                                              const float* __restrict__ beta,
                                              float* __restrict__ Eout)
{
    __shared__ __align__(16) unsigned char F8[96 * FRS8];   // 40,704 B
    __shared__ __align__(16) float sOwn[2][16];
    __shared__ int   sE[96];
    __shared__ float sDnb[96];
    __shared__ int   sDpos[96];
    __shared__ float Psum[96][4];
    __shared__ float Psq[96][4];

    const int row0 = blockIdx.x * 2;
    const int b = row0 / L_;
    const int tid = threadIdx.x;

    // phase 0: per-edge metadata (96 threads) + own atoms (8 threads)
    if (tid < 96) {
        int r2 = (tid >= 48) ? 1 : 0;
        int row = row0 + r2;
        int kl = tid - r2 * 48;
        int j = eidx[row * K_ + kl];
        sE[tid] = j;
        sDnb[tid] = dnb[row * K_ + kl];
        int off = Ridx[row] - Ridx[b * L_ + j];
        int ch = (chain[row] == chain[b * L_ + j]) ? 1 : 0;
        sDpos[tid] = ch ? min(max(off + 32, 0), 64) : 65;
    } else if (tid < 104) {
        int part = tid - 96;      // 0..7
        int r2 = part >> 2;
        *(float4*)(&sOwn[r2][(part & 3) * 4]) =
            *(const float4*)(atoms + (size_t)(row0 + r2) * 16 + (part & 3) * 4);
    }
    __syncthreads();

    // phase F: fused distance + LUT-RBF -> fp8, both rows (240 threads x 10)
    if (tid < 240) {
        const int k = tid / 5;
        const int dd0 = tid - k * 5;
        #pragma unroll
        for (int r2 = 0; r2 < 2; ++r2) {
            const int e = r2 * 48 + k;
            const float* pj = atoms + ((size_t)b * L_ + sE[e]) * 16;
            unsigned char* Fk = F8 + e * FRS8;
            #pragma unroll
            for (int s5 = 0; s5 < 5; ++s5) {
                const int dd = dd0 + 5 * s5;
                float D;
                if (dd == 0) {
                    D = sDnb[e];
                } else {
                    int pr = PAIRC[dd - 1];
                    int ai = pr >> 3, bi = pr & 7;
                    float dx = sOwn[r2][ai * 3 + 0] - pj[bi * 3 + 0];
                    float dy = sOwn[r2][ai * 3 + 1] - pj[bi * 3 + 1];
                    float dz = sOwn[r2][ai * 3 + 2] - pj[bi * 3 + 2];
                    D = sqrtf(fmaf(dz, dz, fmaf(dy, dy, dx * dx)) + 1e-6f);
                }
                float Dc = fminf(D, 29.984375f);
                int idx = (int)fmaf(Dc, 64.0f, 0.5f);
                uint4 v = LUT[idx];
                *(uint4*)(Fk + 16 + dd * 16) = v;
            }
        }
    }
    for (int s2 = tid; s2 < 96 * 16; s2 += 256) {
        int e = s2 >> 4, r = s2 & 15;
        float v = posW[sDpos[e] * 16 + r] + posb[r];
        int w = __builtin_amdgcn_cvt_pk_fp8_f32(v, v, 0, false);
        F8[e * FRS8 + r] = (unsigned char)(w & 0xff);
    }
    __syncthreads();

    // fp8 MFMA GEMM: C[96][128] = F[96][416] @ W[416][128] (paired-col Wt8, B shared by both rows)
    const int lane = tid & 63;
    const int wv = tid >> 6;
    const int l15 = lane & 15;
    const int lhi = lane >> 4;

    f32x4 acc[6][2];
    #pragma unroll
    for (int mt = 0; mt < 6; ++mt)
        #pragma unroll
        for (int nn = 0; nn < 2; ++nn)
            acc[mt][nn] = (f32x4){0.f, 0.f, 0.f, 0.f};

    const unsigned char* wp = Wt8 + wv * 1024 + l15 * 32 + lhi * 8;
    long bc0 = *(const long*)(wp);
    long bc1 = *(const long*)(wp + 512);

    #pragma unroll 1
    for (int kt = 0; kt < 13; ++kt) {
        long bn0 = 0, bn1 = 0;
        if (kt < 12) {
            bn0 = *(const long*)(wp + (kt + 1) * 4096);
            bn1 = *(const long*)(wp + (kt + 1) * 4096 + 512);
        }
        const int k0 = kt * 32 + lhi * 8;
        #pragma unroll
        for (int mt = 0; mt < 6; ++mt) {
            long a = *(const long*)(F8 + (mt * 16 + l15) * FRS8 + k0);
            acc[mt][0] = __builtin_amdgcn_mfma_f32_16x16x32_fp8_fp8(a, bc0, acc[mt][0], 0, 0, 0);
            acc[mt][1] = __builtin_amdgcn_mfma_f32_16x16x32_fp8_fp8(a, bc1, acc[mt][1], 0, 0, 0);
        }
        bc0 = bn0;
        bc1 = bn1;
    }

    // LayerNorm from fragments; fragment nn holds col c0p+nn (adjacent)
    #pragma unroll
    for (int mt = 0; mt < 6; ++mt) {
        #pragma unroll
        for (int r = 0; r < 4; ++r) {
            float v0 = acc[mt][0][r], v1 = acc[mt][1][r];
            float sv = v0 + v1;
            float q = v0 * v0 + v1 * v1;
            #pragma unroll
            for (int off = 1; off < 16; off <<= 1) {
                sv += __shfl_xor(sv, off);
                q += __shfl_xor(q, off);
            }
            if (l15 == 0) {
                int er = mt * 16 + lhi * 4 + r;
                Psum[er][wv] = sv;
                Psq[er][wv] = q;
            }
        }
    }
    __syncthreads();

    const int c0p = wv * 32 + 2 * l15;
    float2 g2 = *(const float2*)(gamma + c0p);
    float2 b2 = *(const float2*)(beta + c0p);

    #pragma unroll
    for (int mt = 0; mt < 6; ++mt) {
        #pragma unroll
        for (int r = 0; r < 4; ++r) {
            int er = mt * 16 + lhi * 4 + r;
            float sv = Psum[er][0] + Psum[er][1] + Psum[er][2] + Psum[er][3];
            float q = Psq[er][0] + Psq[er][1] + Psq[er][2] + Psq[er][3];
            float mu = sv * (1.0f / 128.0f);
            float var = q * (1.0f / 128.0f) - mu * mu;
            float inv = 1.0f / sqrtf(var + 1e-5f);
            int row = row0 + (er >= 48 ? 1 : 0);
            int kl = er & 47;
            float2 o;
            o.x = (acc[mt][0][r] - mu) * inv * g2.x + b2.x;
            o.y = (acc[mt][1][r] - mu) * inv * g2.y + b2.y;
            *(float2*)(Eout + ((size_t)row * K_ + kl) * 128 + c0p) = o;
        }
    }
}

extern "C" void kernel_launch(void* const* d_in, const int* in_sizes, int n_in,
                              void* d_out, int out_size, void* d_ws, size_t ws_size,
                              hipStream_t stream) {
    const float* X     = (const float*)d_in[0];
    const float* mask  = (const float*)d_in[1];
    const int*   Ridx  = (const int*)d_in[2];
    const int*   chain = (const int*)d_in[3];
    const float* posW  = (const float*)d_in[4];
    const float* posb  = (const float*)d_in[5];
    const float* edgeW = (const float*)d_in[6];
    const float* gamma = (const float*)d_in[7];
    const float* beta  = (const float*)d_in[8];

    float* out   = (float*)d_out;
    float* Eout  = out;
    float* EidxF = out + (size_t)B_ * L_ * K_ * NOUT;

    float* atoms = (float*)d_ws;                                  // B*L*16 floats
    float* CaA4  = atoms + (size_t)B_ * L_ * 16;                  // B*L*4 floats
    int*   eidx  = (int*)(CaA4 + (size_t)B_ * L_ * 4);            // B*L*K
    float* dnb   = (float*)(eidx + (size_t)B_ * L_ * K_);         // B*L*K
    unsigned char* Wt8 = (unsigned char*)(dnb + (size_t)B_ * L_ * K_);  // 53,248 B
    uint4* LUT   = (uint4*)(Wt8 + 53248);                         // 30,720 B

    hipLaunchKernelGGL(k_prep, dim3(60 + (B_ * L_ + 255) / 256), dim3(256), 0, stream,
                       X, mask, edgeW, atoms, CaA4, Wt8, LUT);
    hipLaunchKernelGGL(k_topk, dim3(B_ * L_ / 2), dim3(256), 0, stream,
                       CaA4, eidx, dnb, EidxF);
    hipLaunchKernelGGL(k_edge, dim3(B_ * L_ / 2), dim3(256), 0, stream,
                       atoms, eidx, dnb, Ridx, chain, posW, posb, Wt8, LUT, gamma, beta, Eout);
}

// Round 19
// 154.772 us; speedup vs baseline: 1.0377x; 1.0377x over previous
//
#include <hip/hip_runtime.h>
#include <hip/hip_bf16.h>
#include <stdint.h>
#include <math.h>

#define B_   2
#define L_   3072
#define K_   48
#define FDIM 416
#define NOUT 128
#define FRS8 424    // F row stride (fp8 bytes), 8B-aligned
#define NLUT 1920   // RBF LUT entries: D in [0,30) step 1/64

// PAIRC[dd] = ai*8+bi for pair dd (dd = 1..24 uses PAIRC[dd-1])
__device__ const unsigned char PAIRC[24] = {
    0, 18, 27, 36, 8, 10, 11, 12, 2, 3, 4, 34, 35, 26,
    1, 17, 25, 33, 16, 24, 32, 20, 28, 19
};

typedef __attribute__((ext_vector_type(4))) float f32x4;

// ---------- kernel P: Wt8 fragment-order fp8 (paired-column) + RBF LUT + frames ----------
// Wt8 slot (kt,nt,l15,lhi,e) <- edgeW[k][n], k = kt*32+lhi*8+e,
// n = (nt>>1)*32 + 2*l15 + (nt&1)
__global__ __launch_bounds__(256) void k_prep(const float* __restrict__ X,
                                              const float* __restrict__ mask,
                                              const float* __restrict__ edgeW,
                                              float* __restrict__ atoms,
                                              float* __restrict__ CaA4,
                                              unsigned char* __restrict__ Wt8,
                                              uint4* __restrict__ LUT)
{
    const int bid = blockIdx.x;
    if (bid < 52) {
        int idx4 = bid * 256 + threadIdx.x;        // dword index, 0..13311
        int b = idx4 * 4;
        int lhi = (b >> 3) & 3;
        int l15 = (b >> 5) & 15;
        int nt  = (b >> 9) & 7;
        int kt  = b >> 12;
        int n = (nt >> 1) * 32 + 2 * l15 + (nt & 1);
        int kbase = kt * 32 + lhi * 8 + (b & 7);
        float v0 = edgeW[(kbase + 0) * NOUT + n];
        float v1 = edgeW[(kbase + 1) * NOUT + n];
        float v2 = edgeW[(kbase + 2) * NOUT + n];
        float v3 = edgeW[(kbase + 3) * NOUT + n];
        int w = __builtin_amdgcn_cvt_pk_fp8_f32(v0, v1, 0, false);
        w = __builtin_amdgcn_cvt_pk_fp8_f32(v2, v3, w, true);
        ((unsigned int*)Wt8)[idx4] = (unsigned int)w;
    } else if (bid < 60) {
        int e = (bid - 52) * 256 + threadIdx.x;    // LUT entry
        if (e >= NLUT) return;
        float D = (float)e * 0.015625f;            // 1/64
        float z = (D - 2.0f) * 0.8f;
        unsigned int u[4];
        #pragma unroll
        for (int p = 0; p < 4; ++p) {
            float e0 = __expf(-(z * z)); z -= 1.0666667f;
            float e1 = __expf(-(z * z)); z -= 1.0666667f;
            float e2 = __expf(-(z * z)); z -= 1.0666667f;
            float e3 = __expf(-(z * z)); z -= 1.0666667f;
            int w = __builtin_amdgcn_cvt_pk_fp8_f32(e0, e1, 0, false);
            w = __builtin_amdgcn_cvt_pk_fp8_f32(e2, e3, w, true);
            u[p] = (unsigned int)w;
        }
        LUT[e] = make_uint4(u[0], u[1], u[2], u[3]);
    } else {
        int row = (bid - 60) * 256 + threadIdx.x;
        if (row >= B_ * L_) return;
        const float* x = X + row * 12;
        float nx = x[0], ny = x[1], nz = x[2];
        float cax = x[3], cay = x[4], caz = x[5];
        float cx = x[6], cy = x[7], cz = x[8];
        float ox = x[9], oy = x[10], oz = x[11];
        float bx = cax - nx, by = cay - ny, bz = caz - nz;
        float vx = cx - cax, vy = cy - cay, vz = cz - caz;
        float axv = by * vz - bz * vy;
        float ayv = bz * vx - bx * vz;
        float azv = bx * vy - by * vx;
        float cbx = -0.58273431f * axv + 0.56802827f * bx - 0.54067466f * vx + cax;
        float cby = -0.58273431f * ayv + 0.56802827f * by - 0.54067466f * vy + cay;
        float cbz = -0.58273431f * azv + 0.56802827f * bz - 0.54067466f * vz + caz;
        float* A = atoms + row * 16;
        A[0] = nx;  A[1] = ny;  A[2] = nz;
        A[3] = cax; A[4] = cay; A[5] = caz;
        A[6] = cx;  A[7] = cy;  A[8] = cz;
        A[9] = ox;  A[10] = oy; A[11] = oz;
        A[12] = cbx; A[13] = cby; A[14] = cbz;
        A[15] = 0.f;
        float4 c4 = make_float4(cax, cay, caz, mask[row]);
        *(float4*)(CaA4 + row * 4) = c4;
    }
}

// ---- kernel B: top-48. f32 dist^2 bucketing (2048 buckets, +2 slop) -> f64 exact
// ---- refine -> bitonic. Selection bit-identical to passing grid.
__global__ __launch_bounds__(256) void k_topk(const float* __restrict__ CaA4,
                                              int* __restrict__ eidx,
                                              float* __restrict__ dnb,
                                              float* __restrict__ out_eidx_f)
{
    __shared__ __align__(16) unsigned int SH[3072];   // 12 KB
    unsigned int* hist  = SH;
    unsigned int* candJ = SH + 2048;
    unsigned long long* candK = (unsigned long long*)SH;
    __shared__ unsigned int swave[4];
    __shared__ int sP;
    __shared__ unsigned int sCnt;

    const int row = blockIdx.x;
    const int b = row / L_;
    const int tid = threadIdx.x;
    const int lane = tid & 63;
    const int wv = tid >> 6;

    #pragma unroll
    for (int i = 0; i < 8; ++i) hist[tid + 256 * i] = 0;
    if (tid == 0) sCnt = 0;

    const float4 me = *(const float4*)(CaA4 + row * 4);
    const float4* Cb = (const float4*)(CaA4 + (size_t)b * L_ * 4);
    __syncthreads();

    unsigned int bits[12];
    #pragma unroll
    for (int m = 0; m < 12; ++m) {
        int j = tid + 256 * m;
        float4 nb = Cb[j];
        float dx = me.x - nb.x;
        float dy = me.y - nb.y;
        float dz = me.z - nb.z;
        float s = fmaf(dz, dz, fmaf(dy, dy, dx * dx)) + 1e-6f;
        bool live = (me.w * nb.w) != 0.0f;
        bits[m] = live ? __float_as_uint(s) : 0x7F800000u;
        atomicAdd(&hist[bits[m] >> 20], 1u);
    }
    __syncthreads();

    unsigned int loc[8];
    unsigned int s = 0;
    #pragma unroll
    for (int i = 0; i < 8; ++i) { loc[i] = hist[tid * 8 + i]; s += loc[i]; }
    unsigned int sc = s;
    #pragma unroll
    for (int off = 1; off < 64; off <<= 1) {
        unsigned int o = __shfl_up(sc, off);
        if (lane >= off) sc += o;
    }
    if (lane == 63) swave[wv] = sc;
    __syncthreads();
    unsigned int base = 0;
    #pragma unroll
    for (int w = 0; w < 4; ++w) if (w < wv) base += swave[w];
    unsigned int cum = base + sc - s;
    #pragma unroll
    for (int i = 0; i < 8; ++i) {
        unsigned int c = loc[i];
        if (cum < K_ && cum + c >= K_) sP = tid * 8 + i;
        cum += c;
    }
    __syncthreads();
    const unsigned int Pth = (unsigned int)sP + 2;

    #pragma unroll
    for (int m = 0; m < 12; ++m) {
        if ((bits[m] >> 20) <= Pth) {
            unsigned int pos = atomicAdd(&sCnt, 1u);
            if (pos < 1024) candJ[pos] = (unsigned)(tid + 256 * m);
        }
    }
    __syncthreads();
    int cnt = (int)sCnt;
    if (cnt > 1024) cnt = 1024;

    const double cax = (double)me.x, cay = (double)me.y, caz = (double)me.z;
    for (int i = tid; i < cnt; i += 256) {
        int j = (int)candJ[i];
        float4 nb = Cb[j];
        double dx = cax - (double)nb.x;
        double dy = cay - (double)nb.y;
        double dz = caz - (double)nb.z;
        double ss = dx * dx;
        ss = ss + dy * dy;
        ss = ss + dz * dz;
        ss = ss + 1e-6;
        float v = (float)sqrt(ss);
        candK[i] = ((unsigned long long)__float_as_uint(v) << 32) | (unsigned)j;
    }
    __syncthreads();

    if (cnt <= 64) {
        if (wv == 0) {
            unsigned long long k = (lane < cnt) ? candK[lane] : ~0ull;
            #pragma unroll
            for (int size = 2; size <= 64; size <<= 1) {
                #pragma unroll
                for (int stride = size >> 1; stride >= 1; stride >>= 1) {
                    unsigned long long o = __shfl_xor(k, stride);
                    bool low = (lane & stride) == 0;
                    bool up = (lane & size) == 0 || size == 64;
                    unsigned long long mn = k < o ? k : o;
                    unsigned long long mx = k < o ? o : k;
                    k = (low == up) ? mn : mx;
                }
            }
            if (lane < K_) {
                int gj = (int)(unsigned)(k & 0xffffffffu);
                eidx[row * K_ + lane] = gj;
                dnb[row * K_ + lane] = __uint_as_float((unsigned)(k >> 32));
                out_eidx_f[row * K_ + lane] = (float)gj;
            }
        }
    } else {
        int M2 = 128;
        while (M2 < cnt) M2 <<= 1;
        for (int i = cnt + tid; i < M2; i += 256) candK[i] = ~0ull;
        for (int size = 2; size <= M2; size <<= 1) {
            for (int stride = size >> 1; stride > 0; stride >>= 1) {
                __syncthreads();
                for (int i = tid; i < M2; i += 256) {
                    int p = i ^ stride;
                    if (p > i) {
                        unsigned long long a = candK[i];
                        unsigned long long c2 = candK[p];
                        bool up = ((i & size) == 0);
                        if ((a > c2) == up) { candK[i] = c2; candK[p] = a; }
                    }
                }
            }
        }
        __syncthreads();
        if (tid < K_) {
            unsigned long long g = candK[tid];
            int gj = (int)(unsigned)(g & 0xffffffffu);
            eidx[row * K_ + tid] = gj;
            dnb[row * K_ + tid] = __uint_as_float((unsigned)(g >> 32));
            out_eidx_f[row * K_ + tid] = (float)gj;
        }
    }
}

// ---------------- kernel C: 512 threads / 1 row: features -> fp8 MFMA -> register LN ----------------
// 8 waves: wave w owns N-tile nt=w (16 cols), M-tiles 0..2. LDS ~24 KB, 4 blocks/CU = 32 waves.
__global__ __launch_bounds__(512) void k_edge(const float* __restrict__ atoms,
                                              const int* __restrict__ eidx,
                                              const float* __restrict__ dnb,
                                              const int* __restrict__ Ridx,
                                              const int* __restrict__ chain,
                                              const float* __restrict__ posW,
                                              const float* __restrict__ posb,
                                              const unsigned char* __restrict__ Wt8,
                                              const uint4* __restrict__ LUT,
                                              const float* __restrict__ gamma,
                                              const float* __restrict__ beta,
                                              float* __restrict__ Eout)
{
    __shared__ __align__(16) unsigned char F8[K_ * FRS8];   // 20,352 B
    __shared__ __align__(16) float sOwn[16];
    __shared__ int   sE[K_];
    __shared__ float sDnb[K_];
    __shared__ int   sDpos[K_];
    __shared__ float Psum[K_][8];
    __shared__ float Psq[K_][8];

    const int row = blockIdx.x;
    const int b = row / L_;
    const int tid = threadIdx.x;

    // phase 0: per-edge metadata (48 threads) + own atoms (4 threads)
    if (tid < K_) {
        int j = eidx[row * K_ + tid];
        sE[tid] = j;
        sDnb[tid] = dnb[row * K_ + tid];
        int off = Ridx[row] - Ridx[b * L_ + j];
        int ch = (chain[row] == chain[b * L_ + j]) ? 1 : 0;
        sDpos[tid] = ch ? min(max(off + 32, 0), 64) : 65;
    } else if (tid < K_ + 4) {
        int part = tid - K_;
        *(float4*)(&sOwn[part * 4]) = *(const float4*)(atoms + (size_t)row * 16 + part * 4);
    }
    __syncthreads();

    // phase F: fused distance + LUT-RBF -> fp8 (480 threads, <=3 dd each)
    if (tid < 480) {
        const int k = tid / 10;
        const int dd0 = tid - k * 10;
        const float* pj = atoms + ((size_t)b * L_ + sE[k]) * 16;
        unsigned char* Fk = F8 + k * FRS8;
        #pragma unroll
        for (int s3 = 0; s3 < 3; ++s3) {
            const int dd = dd0 + 10 * s3;
            if (dd >= 25) break;
            float D;
            if (dd == 0) {
                D = sDnb[k];
            } else {
                int pr = PAIRC[dd - 1];
                int ai = pr >> 3, bi = pr & 7;
                float dx = sOwn[ai * 3 + 0] - pj[bi * 3 + 0];
                float dy = sOwn[ai * 3 + 1] - pj[bi * 3 + 1];
                float dz = sOwn[ai * 3 + 2] - pj[bi * 3 + 2];
                D = sqrtf(fmaf(dz, dz, fmaf(dy, dy, dx * dx)) + 1e-6f);
            }
            float Dc = fminf(D, 29.984375f);
            int idx = (int)fmaf(Dc, 64.0f, 0.5f);
            uint4 v = LUT[idx];
            *(uint4*)(Fk + 16 + dd * 16) = v;
        }
    }
    for (int s2 = tid; s2 < K_ * 16; s2 += 512) {
        int k = s2 >> 4, r = s2 & 15;
        float v = posW[sDpos[k] * 16 + r] + posb[r];
        int w = __builtin_amdgcn_cvt_pk_fp8_f32(v, v, 0, false);
        F8[k * FRS8 + r] = (unsigned char)(w & 0xff);
    }
    __syncthreads();

    // fp8 MFMA GEMM: C[48][128] = F[48][416] @ W[416][128]; wave w -> nt = w
    const int lane = tid & 63;
    const int wv = tid >> 6;       // 0..7 = nt
    const int l15 = lane & 15;
    const int lhi = lane >> 4;

    f32x4 acc[3];
    #pragma unroll
    for (int mt = 0; mt < 3; ++mt)
        acc[mt] = (f32x4){0.f, 0.f, 0.f, 0.f};

    const unsigned char* wp = Wt8 + wv * 512 + l15 * 32 + lhi * 8;
    long bc = *(const long*)(wp);

    #pragma unroll 1
    for (int kt = 0; kt < 13; ++kt) {
        long bn = 0;
        if (kt < 12) bn = *(const long*)(wp + (kt + 1) * 4096);
        const int k0 = kt * 32 + lhi * 8;
        long a0 = *(const long*)(F8 + (l15) * FRS8 + k0);
        long a1 = *(const long*)(F8 + (16 + l15) * FRS8 + k0);
        long a2 = *(const long*)(F8 + (32 + l15) * FRS8 + k0);
        acc[0] = __builtin_amdgcn_mfma_f32_16x16x32_fp8_fp8(a0, bc, acc[0], 0, 0, 0);
        acc[1] = __builtin_amdgcn_mfma_f32_16x16x32_fp8_fp8(a1, bc, acc[1], 0, 0, 0);
        acc[2] = __builtin_amdgcn_mfma_f32_16x16x32_fp8_fp8(a2, bc, acc[2], 0, 0, 0);
        bc = bn;
    }

    // LayerNorm partials: 16-lane reduce per (mt, r) -> Psum/Psq[er][wv]
    #pragma unroll
    for (int mt = 0; mt < 3; ++mt) {
        #pragma unroll
        for (int r = 0; r < 4; ++r) {
            float v0 = acc[mt][r];
            float sv = v0;
            float q = v0 * v0;
            #pragma unroll
            for (int off = 1; off < 16; off <<= 1) {
                sv += __shfl_xor(sv, off);
                q += __shfl_xor(q, off);
            }
            if (l15 == 0) {
                int er = mt * 16 + lhi * 4 + r;
                Psum[er][wv] = sv;
                Psq[er][wv] = q;
            }
        }
    }
    __syncthreads();

    // lane's column: c0 = (wv>>1)*32 + 2*l15 + (wv&1)
    const int c0 = (wv >> 1) * 32 + 2 * l15 + (wv & 1);
    float g1 = gamma[c0];
    float b1 = beta[c0];

    #pragma unroll
    for (int mt = 0; mt < 3; ++mt) {
        #pragma unroll
        for (int r = 0; r < 4; ++r) {
            int er = mt * 16 + lhi * 4 + r;
            float sv = 0.f, q = 0.f;
            #pragma unroll
            for (int w = 0; w < 8; ++w) { sv += Psum[er][w]; q += Psq[er][w]; }
            float mu = sv * (1.0f / 128.0f);
            float var = q * (1.0f / 128.0f) - mu * mu;
            float inv = 1.0f / sqrtf(var + 1e-5f);
            Eout[((size_t)row * K_ + er) * 128 + c0] = (acc[mt][r] - mu) * inv * g1 + b1;
        }
    }
}

extern "C" void kernel_launch(void* const* d_in, const int* in_sizes, int n_in,
                              void* d_out, int out_size, void* d_ws, size_t ws_size,
                              hipStream_t stream) {
    const float* X     = (const float*)d_in[0];
    const float* mask  = (const float*)d_in[1];
    const int*   Ridx  = (const int*)d_in[2];
    const int*   chain = (const int*)d_in[3];
    const float* posW  = (const float*)d_in[4];
    const float* posb  = (const float*)d_in[5];
    const float* edgeW = (const float*)d_in[6];
    const float* gamma = (const float*)d_in[7];
    const float* beta  = (const float*)d_in[8];

    float* out   = (float*)d_out;
    float* Eout  = out;
    float* EidxF = out + (size_t)B_ * L_ * K_ * NOUT;

    float* atoms = (float*)d_ws;                                  // B*L*16 floats
    float* CaA4  = atoms + (size_t)B_ * L_ * 16;                  // B*L*4 floats
    int*   eidx  = (int*)(CaA4 + (size_t)B_ * L_ * 4);            // B*L*K
    float* dnb   = (float*)(eidx + (size_t)B_ * L_ * K_);         // B*L*K
    unsigned char* Wt8 = (unsigned char*)(dnb + (size_t)B_ * L_ * K_);  // 53,248 B
    uint4* LUT   = (uint4*)(Wt8 + 53248);                         // 30,720 B

    hipLaunchKernelGGL(k_prep, dim3(60 + (B_ * L_ + 255) / 256), dim3(256), 0, stream,
                       X, mask, edgeW, atoms, CaA4, Wt8, LUT);
    hipLaunchKernelGGL(k_topk, dim3(B_ * L_), dim3(256), 0, stream,
                       CaA4, eidx, dnb, EidxF);
    hipLaunchKernelGGL(k_edge, dim3(B_ * L_), dim3(512), 0, stream,
                       atoms, eidx, dnb, Ridx, chain, posW, posb, Wt8, LUT, gamma, beta, Eout);
}

// Round 20
// 116.453 us; speedup vs baseline: 1.3791x; 1.3291x over previous
//
#include <hip/hip_runtime.h>
#include <hip/hip_bf16.h>
#include <stdint.h>
#include <math.h>

#define B_   2
#define L_   3072
#define K_   48
#define FDIM 416
#define NOUT 128
#define FRS8 424    // F row stride (fp8 bytes), 8B-aligned
#define NLUT 1920   // RBF LUT entries: D in [0,30) step 1/64

// PAIRC[dd] = ai*8+bi for pair dd (dd = 1..24 uses PAIRC[dd-1])
__device__ const unsigned char PAIRC[24] = {
    0, 18, 27, 36, 8, 10, 11, 12, 2, 3, 4, 34, 35, 26,
    1, 17, 25, 33, 16, 24, 32, 20, 28, 19
};

typedef __attribute__((ext_vector_type(4))) float f32x4;

// ---------- kernel P: Wt8 fragment-order fp8 (paired-column) + RBF LUT + frames ----------
__global__ __launch_bounds__(256) void k_prep(const float* __restrict__ X,
                                              const float* __restrict__ mask,
                                              const float* __restrict__ edgeW,
                                              float* __restrict__ atoms,
                                              float* __restrict__ CaA4,
                                              unsigned char* __restrict__ Wt8,
                                              uint4* __restrict__ LUT)
{
    const int bid = blockIdx.x;
    if (bid < 52) {
        int idx4 = bid * 256 + threadIdx.x;        // dword index, 0..13311
        int b = idx4 * 4;
        int lhi = (b >> 3) & 3;
        int l15 = (b >> 5) & 15;
        int nt  = (b >> 9) & 7;
        int kt  = b >> 12;
        int n = (nt >> 1) * 32 + 2 * l15 + (nt & 1);
        int kbase = kt * 32 + lhi * 8 + (b & 7);
        float v0 = edgeW[(kbase + 0) * NOUT + n];
        float v1 = edgeW[(kbase + 1) * NOUT + n];
        float v2 = edgeW[(kbase + 2) * NOUT + n];
        float v3 = edgeW[(kbase + 3) * NOUT + n];
        int w = __builtin_amdgcn_cvt_pk_fp8_f32(v0, v1, 0, false);
        w = __builtin_amdgcn_cvt_pk_fp8_f32(v2, v3, w, true);
        ((unsigned int*)Wt8)[idx4] = (unsigned int)w;
    } else if (bid < 60) {
        int e = (bid - 52) * 256 + threadIdx.x;    // LUT entry
        if (e >= NLUT) return;
        float D = (float)e * 0.015625f;            // 1/64
        float z = (D - 2.0f) * 0.8f;
        unsigned int u[4];
        #pragma unroll
        for (int p = 0; p < 4; ++p) {
            float e0 = __expf(-(z * z)); z -= 1.0666667f;
            float e1 = __expf(-(z * z)); z -= 1.0666667f;
            float e2 = __expf(-(z * z)); z -= 1.0666667f;
            float e3 = __expf(-(z * z)); z -= 1.0666667f;
            int w = __builtin_amdgcn_cvt_pk_fp8_f32(e0, e1, 0, false);
            w = __builtin_amdgcn_cvt_pk_fp8_f32(e2, e3, w, true);
            u[p] = (unsigned int)w;
        }
        LUT[e] = make_uint4(u[0], u[1], u[2], u[3]);
    } else {
        int row = (bid - 60) * 256 + threadIdx.x;
        if (row >= B_ * L_) return;
        const float* x = X + row * 12;
        float nx = x[0], ny = x[1], nz = x[2];
        float cax = x[3], cay = x[4], caz = x[5];
        float cx = x[6], cy = x[7], cz = x[8];
        float ox = x[9], oy = x[10], oz = x[11];
        float bx = cax - nx, by = cay - ny, bz = caz - nz;
        float vx = cx - cax, vy = cy - cay, vz = cz - caz;
        float axv = by * vz - bz * vy;
        float ayv = bz * vx - bx * vz;
        float azv = bx * vy - by * vx;
        float cbx = -0.58273431f * axv + 0.56802827f * bx - 0.54067466f * vx + cax;
        float cby = -0.58273431f * ayv + 0.56802827f * by - 0.54067466f * vy + cay;
        float cbz = -0.58273431f * azv + 0.56802827f * bz - 0.54067466f * vz + caz;
        float* A = atoms + row * 16;
        A[0] = nx;  A[1] = ny;  A[2] = nz;
        A[3] = cax; A[4] = cay; A[5] = caz;
        A[6] = cx;  A[7] = cy;  A[8] = cz;
        A[9] = ox;  A[10] = oy; A[11] = oz;
        A[12] = cbx; A[13] = cby; A[14] = cbz;
        A[15] = 0.f;
        float4 c4 = make_float4(cax, cay, caz, mask[row]);
        *(float4*)(CaA4 + row * 4) = c4;
    }
}

// ---- kernel B: top-48. f32 dist^2 bucketing (2048 buckets, +2 slop) -> f64 exact
// ---- refine -> bitonic. Selection bit-identical to passing grid.
__global__ __launch_bounds__(256) void k_topk(const float* __restrict__ CaA4,
                                              int* __restrict__ eidx,
                                              float* __restrict__ dnb,
                                              float* __restrict__ out_eidx_f)
{
    __shared__ __align__(16) unsigned int SH[3072];   // 12 KB
    unsigned int* hist  = SH;
    unsigned int* candJ = SH + 2048;
    unsigned long long* candK = (unsigned long long*)SH;
    __shared__ unsigned int swave[4];
    __shared__ int sP;
    __shared__ unsigned int sCnt;

    const int row = blockIdx.x;
    const int b = row / L_;
    const int tid = threadIdx.x;
    const int lane = tid & 63;
    const int wv = tid >> 6;

    #pragma unroll
    for (int i = 0; i < 8; ++i) hist[tid + 256 * i] = 0;
    if (tid == 0) sCnt = 0;

    const float4 me = *(const float4*)(CaA4 + row * 4);
    const float4* Cb = (const float4*)(CaA4 + (size_t)b * L_ * 4);
    __syncthreads();

    unsigned int bits[12];
    #pragma unroll
    for (int m = 0; m < 12; ++m) {
        int j = tid + 256 * m;
        float4 nb = Cb[j];
        float dx = me.x - nb.x;
        float dy = me.y - nb.y;
        float dz = me.z - nb.z;
        float s = fmaf(dz, dz, fmaf(dy, dy, dx * dx)) + 1e-6f;
        bool live = (me.w * nb.w) != 0.0f;
        bits[m] = live ? __float_as_uint(s) : 0x7F800000u;
        atomicAdd(&hist[bits[m] >> 20], 1u);
    }
    __syncthreads();

    unsigned int loc[8];
    unsigned int s = 0;
    #pragma unroll
    for (int i = 0; i < 8; ++i) { loc[i] = hist[tid * 8 + i]; s += loc[i]; }
    unsigned int sc = s;
    #pragma unroll
    for (int off = 1; off < 64; off <<= 1) {
        unsigned int o = __shfl_up(sc, off);
        if (lane >= off) sc += o;
    }
    if (lane == 63) swave[wv] = sc;
    __syncthreads();
    unsigned int base = 0;
    #pragma unroll
    for (int w = 0; w < 4; ++w) if (w < wv) base += swave[w];
    unsigned int cum = base + sc - s;
    #pragma unroll
    for (int i = 0; i < 8; ++i) {
        unsigned int c = loc[i];
        if (cum < K_ && cum + c >= K_) sP = tid * 8 + i;
        cum += c;
    }
    __syncthreads();
    const unsigned int Pth = (unsigned int)sP + 2;

    #pragma unroll
    for (int m = 0; m < 12; ++m) {
        if ((bits[m] >> 20) <= Pth) {
            unsigned int pos = atomicAdd(&sCnt, 1u);
            if (pos < 1024) candJ[pos] = (unsigned)(tid + 256 * m);
        }
    }
    __syncthreads();
    int cnt = (int)sCnt;
    if (cnt > 1024) cnt = 1024;

    const double cax = (double)me.x, cay = (double)me.y, caz = (double)me.z;
    for (int i = tid; i < cnt; i += 256) {
        int j = (int)candJ[i];
        float4 nb = Cb[j];
        double dx = cax - (double)nb.x;
        double dy = cay - (double)nb.y;
        double dz = caz - (double)nb.z;
        double ss = dx * dx;
        ss = ss + dy * dy;
        ss = ss + dz * dz;
        ss = ss + 1e-6;
        float v = (float)sqrt(ss);
        candK[i] = ((unsigned long long)__float_as_uint(v) << 32) | (unsigned)j;
    }
    __syncthreads();

    if (cnt <= 64) {
        if (wv == 0) {
            unsigned long long k = (lane < cnt) ? candK[lane] : ~0ull;
            #pragma unroll
            for (int size = 2; size <= 64; size <<= 1) {
                #pragma unroll
                for (int stride = size >> 1; stride >= 1; stride >>= 1) {
                    unsigned long long o = __shfl_xor(k, stride);
                    bool low = (lane & stride) == 0;
                    bool up = (lane & size) == 0 || size == 64;
                    unsigned long long mn = k < o ? k : o;
                    unsigned long long mx = k < o ? o : k;
                    k = (low == up) ? mn : mx;
                }
            }
            if (lane < K_) {
                int gj = (int)(unsigned)(k & 0xffffffffu);
                eidx[row * K_ + lane] = gj;
                dnb[row * K_ + lane] = __uint_as_float((unsigned)(k >> 32));
                out_eidx_f[row * K_ + lane] = (float)gj;
            }
        }
    } else {
        int M2 = 128;
        while (M2 < cnt) M2 <<= 1;
        for (int i = cnt + tid; i < M2; i += 256) candK[i] = ~0ull;
        for (int size = 2; size <= M2; size <<= 1) {
            for (int stride = size >> 1; stride > 0; stride >>= 1) {
                __syncthreads();
                for (int i = tid; i < M2; i += 256) {
                    int p = i ^ stride;
                    if (p > i) {
                        unsigned long long a = candK[i];
                        unsigned long long c2 = candK[p];
                        bool up = ((i & size) == 0);
                        if ((a > c2) == up) { candK[i] = c2; candK[p] = a; }
                    }
                }
            }
        }
        __syncthreads();
        if (tid < K_) {
            unsigned long long g = candK[tid];
            int gj = (int)(unsigned)(g & 0xffffffffu);
            eidx[row * K_ + tid] = gj;
            dnb[row * K_ + tid] = __uint_as_float((unsigned)(g >> 32));
            out_eidx_f[row * K_ + tid] = (float)gj;
        }
    }
}

// ---------------- kernel C: direct-gather LUT features -> fp8 MFMA -> shared-LN epilogue ----------------
__global__ __launch_bounds__(256) void k_edge(const float* __restrict__ atoms,
                                              const int* __restrict__ eidx,
                                              const float* __restrict__ dnb,
                                              const int* __restrict__ Ridx,
                                              const int* __restrict__ chain,
                                              const float* __restrict__ posW,
                                              const float* __restrict__ posb,
                                              const unsigned char* __restrict__ Wt8,
                                              const uint4* __restrict__ LUT,
                                              const float* __restrict__ gamma,
                                              const float* __restrict__ beta,
                                              float* __restrict__ Eout)
{
    __shared__ __align__(16) unsigned char F8[K_ * FRS8];   // 20,352 B
    __shared__ __align__(16) float sOwn[16];
    __shared__ int   sE[K_];
    __shared__ float sDnb[K_];
    __shared__ int   sDpos[K_];
    __shared__ float Psum[K_][4];
    __shared__ float Psq[K_][4];
    __shared__ float sMu[K_];
    __shared__ float sInv[K_];

    const int row = blockIdx.x;
    const int b = row / L_;
    const int tid = threadIdx.x;

    // phase 0: per-edge metadata (48 threads) + own atoms (4 threads)
    if (tid < K_) {
        int j = eidx[row * K_ + tid];
        sE[tid] = j;
        sDnb[tid] = dnb[row * K_ + tid];
        int off = Ridx[row] - Ridx[b * L_ + j];
        int ch = (chain[row] == chain[b * L_ + j]) ? 1 : 0;
        sDpos[tid] = ch ? min(max(off + 32, 0), 64) : 65;
    } else if (tid < K_ + 4) {
        int part = tid - K_;
        *(float4*)(&sOwn[part * 4]) = *(const float4*)(atoms + (size_t)row * 16 + part * 4);
    }
    __syncthreads();

    // phase F: fused distance (direct global atom reads, L1-resident) + LUT-RBF -> fp8
    if (tid < 240) {
        const int k = tid / 5;
        const int dd0 = tid - k * 5;
        const float* pj = atoms + ((size_t)b * L_ + sE[k]) * 16;
        unsigned char* Fk = F8 + k * FRS8;
        #pragma unroll
        for (int s5 = 0; s5 < 5; ++s5) {
            const int dd = dd0 + 5 * s5;
            float D;
            if (dd == 0) {
                D = sDnb[k];
            } else {
                int pr = PAIRC[dd - 1];
                int ai = pr >> 3, bi = pr & 7;
                float dx = sOwn[ai * 3 + 0] - pj[bi * 3 + 0];
                float dy = sOwn[ai * 3 + 1] - pj[bi * 3 + 1];
                float dz = sOwn[ai * 3 + 2] - pj[bi * 3 + 2];
                D = sqrtf(fmaf(dz, dz, fmaf(dy, dy, dx * dx)) + 1e-6f);
            }
            float Dc = fminf(D, 29.984375f);
            int idx = (int)fmaf(Dc, 64.0f, 0.5f);
            uint4 v = LUT[idx];
            *(uint4*)(Fk + 16 + dd * 16) = v;
        }
    }
    for (int s2 = tid; s2 < K_ * 16; s2 += 256) {
        int k = s2 >> 4, r = s2 & 15;
        float v = posW[sDpos[k] * 16 + r] + posb[r];
        int w = __builtin_amdgcn_cvt_pk_fp8_f32(v, v, 0, false);
        F8[k * FRS8 + r] = (unsigned char)(w & 0xff);
    }
    __syncthreads();

    // fp8 MFMA GEMM: C[48][128] = F[48][416] @ W[416][128] (paired-col Wt8)
    const int lane = tid & 63;
    const int wv = tid >> 6;
    const int l15 = lane & 15;
    const int lhi = lane >> 4;

    f32x4 acc[3][2];
    #pragma unroll
    for (int mt = 0; mt < 3; ++mt)
        #pragma unroll
        for (int nn = 0; nn < 2; ++nn)
            acc[mt][nn] = (f32x4){0.f, 0.f, 0.f, 0.f};

    const unsigned char* wp = Wt8 + wv * 1024 + l15 * 32 + lhi * 8;
    long bc0 = *(const long*)(wp);
    long bc1 = *(const long*)(wp + 512);

    #pragma unroll 1
    for (int kt = 0; kt < 13; ++kt) {
        long bn0 = 0, bn1 = 0;
        if (kt < 12) {
            bn0 = *(const long*)(wp + (kt + 1) * 4096);
            bn1 = *(const long*)(wp + (kt + 1) * 4096 + 512);
        }
        const int k0 = kt * 32 + lhi * 8;
        long a0 = *(const long*)(F8 + (l15) * FRS8 + k0);
        long a1 = *(const long*)(F8 + (16 + l15) * FRS8 + k0);
        long a2 = *(const long*)(F8 + (32 + l15) * FRS8 + k0);
        acc[0][0] = __builtin_amdgcn_mfma_f32_16x16x32_fp8_fp8(a0, bc0, acc[0][0], 0, 0, 0);
        acc[0][1] = __builtin_amdgcn_mfma_f32_16x16x32_fp8_fp8(a0, bc1, acc[0][1], 0, 0, 0);
        acc[1][0] = __builtin_amdgcn_mfma_f32_16x16x32_fp8_fp8(a1, bc0, acc[1][0], 0, 0, 0);
        acc[1][1] = __builtin_amdgcn_mfma_f32_16x16x32_fp8_fp8(a1, bc1, acc[1][1], 0, 0, 0);
        acc[2][0] = __builtin_amdgcn_mfma_f32_16x16x32_fp8_fp8(a2, bc0, acc[2][0], 0, 0, 0);
        acc[2][1] = __builtin_amdgcn_mfma_f32_16x16x32_fp8_fp8(a2, bc1, acc[2][1], 0, 0, 0);
        bc0 = bn0;
        bc1 = bn1;
    }

    // LN partials: 16-lane shuffle reduce -> Psum/Psq
    #pragma unroll
    for (int mt = 0; mt < 3; ++mt) {
        #pragma unroll
        for (int r = 0; r < 4; ++r) {
            float v0 = acc[mt][0][r], v1 = acc[mt][1][r];
            float sv = v0 + v1;
            float q = v0 * v0 + v1 * v1;
            #pragma unroll
            for (int off = 1; off < 16; off <<= 1) {
                sv += __shfl_xor(sv, off);
                q += __shfl_xor(q, off);
            }
            if (l15 == 0) {
                int er = mt * 16 + lhi * 4 + r;
                Psum[er][wv] = sv;
                Psq[er][wv] = q;
            }
        }
    }
    __syncthreads();

    // LN stats computed ONCE per edge-row by 48 threads (was duplicated 16x per lane x12)
    if (tid < K_) {
        float sv = Psum[tid][0] + Psum[tid][1] + Psum[tid][2] + Psum[tid][3];
        float q  = Psq[tid][0] + Psq[tid][1] + Psq[tid][2] + Psq[tid][3];
        float mu = sv * (1.0f / 128.0f);
        float var = q * (1.0f / 128.0f) - mu * mu;
        sMu[tid] = mu;
        sInv[tid] = 1.0f / sqrtf(var + 1e-5f);
    }
    __syncthreads();

    const int c0p = wv * 32 + 2 * l15;
    float2 g2 = *(const float2*)(gamma + c0p);
    float2 b2 = *(const float2*)(beta + c0p);

    #pragma unroll
    for (int mt = 0; mt < 3; ++mt) {
        #pragma unroll
        for (int r = 0; r < 4; ++r) {
            int er = mt * 16 + lhi * 4 + r;
            float mu = sMu[er];          // LDS broadcast (all 16 lanes same addr)
            float inv = sInv[er];
            float2 o;
            o.x = (acc[mt][0][r] - mu) * inv * g2.x + b2.x;
            o.y = (acc[mt][1][r] - mu) * inv * g2.y + b2.y;
            *(float2*)(Eout + ((size_t)row * K_ + er) * 128 + c0p) = o;
        }
    }
}

extern "C" void kernel_launch(void* const* d_in, const int* in_sizes, int n_in,
                              void* d_out, int out_size, void* d_ws, size_t ws_size,
                              hipStream_t stream) {
    const float* X     = (const float*)d_in[0];
    const float* mask  = (const float*)d_in[1];
    const int*   Ridx  = (const int*)d_in[2];
    const int*   chain = (const int*)d_in[3];
    const float* posW  = (const float*)d_in[4];
    const float* posb  = (const float*)d_in[5];
    const float* edgeW = (const float*)d_in[6];
    const float* gamma = (const float*)d_in[7];
    const float* beta  = (const float*)d_in[8];

    float* out   = (float*)d_out;
    float* Eout  = out;
    float* EidxF = out + (size_t)B_ * L_ * K_ * NOUT;

    float* atoms = (float*)d_ws;                                  // B*L*16 floats
    float* CaA4  = atoms + (size_t)B_ * L_ * 16;                  // B*L*4 floats
    int*   eidx  = (int*)(CaA4 + (size_t)B_ * L_ * 4);            // B*L*K
    float* dnb   = (float*)(eidx + (size_t)B_ * L_ * K_);         // B*L*K
    unsigned char* Wt8 = (unsigned char*)(dnb + (size_t)B_ * L_ * K_);  // 53,248 B
    uint4* LUT   = (uint4*)(Wt8 + 53248);                         // 30,720 B

    hipLaunchKernelGGL(k_prep, dim3(60 + (B_ * L_ + 255) / 256), dim3(256), 0, stream,
                       X, mask, edgeW, atoms, CaA4, Wt8, LUT);
    hipLaunchKernelGGL(k_topk, dim3(B_ * L_), dim3(256), 0, stream,
                       CaA4, eidx, dnb, EidxF);
    hipLaunchKernelGGL(k_edge, dim3(B_ * L_), dim3(256), 0, stream,
                       atoms, eidx, dnb, Ridx, chain, posW, posb, Wt8, LUT, gamma, beta, Eout);
}